// Round 1
// baseline (4545.234 us; speedup 1.0000x reference)
//
#include <hip/hip_runtime.h>
#include <math.h>
#include <stddef.h>

#define L9   9
#define NB   2
#define CF   1024
#define HW   400     // 20*20
#define CH   256
#define TEMPF 20.0f
#define EPSF  1e-12f

// ---------------------------------------------------------------------------
// Kernel 1: partial sums of squares over C for l2norm of fq_feats / fs_feats.
// grid: (18*8, 2 tensors), block 256. partial[t][lb][chunk][ij]
// ---------------------------------------------------------------------------
__global__ __launch_bounds__(256) void norm_partial(const float* __restrict__ fq,
                                                    const float* __restrict__ fs,
                                                    float* __restrict__ partial) {
    int t = blockIdx.y;
    int lb = blockIdx.x >> 3;
    int chunk = blockIdx.x & 7;
    const float* src = (t == 0 ? fq : fs) + (size_t)lb * CF * HW;
    int c0 = chunk * 128;
    int tid = threadIdx.x;
    float acc0 = 0.f, acc1 = 0.f;
    for (int c = c0; c < c0 + 128; ++c) {
        const float* row = src + (size_t)c * HW;
        float v0 = row[tid];
        acc0 = fmaf(v0, v0, acc0);
        if (tid < HW - 256) { float v1 = row[tid + 256]; acc1 = fmaf(v1, v1, acc1); }
    }
    float* dst = partial + ((size_t)(t * 18 + lb) * 8 + chunk) * HW;
    dst[tid] = acc0;
    if (tid < HW - 256) dst[tid + 256] = acc1;
}

// ---------------------------------------------------------------------------
// Kernel 2: finalize inverse norms. invn[t*7200 + lb*400 + ij]
// ---------------------------------------------------------------------------
__global__ __launch_bounds__(256) void norm_finalize(const float* __restrict__ partial,
                                                     float* __restrict__ invn) {
    int idx = blockIdx.x * 256 + threadIdx.x;
    if (idx >= 2 * 18 * HW) return;
    int t_lb = idx / HW;
    int ij = idx - t_lb * HW;
    const float* p = partial + (size_t)t_lb * 8 * HW + ij;
    float ss = 0.f;
    #pragma unroll
    for (int c = 0; c < 8; ++c) ss += p[c * HW];
    invn[idx] = 1.0f / fmaxf(sqrtf(ss), EPSF);
}

// ---------------------------------------------------------------------------
// Kernel 3: correlation GEMM per (l,b): corr[b,l,ij,km] =
//   invq[ij]*invs[km] * sum_c fq[l,b,c,ij]*fs[l,b,c,km]
// grid (7,7,18), block 256 (16x16 threads, 4x4 per thread, 64x64 tile)
// ---------------------------------------------------------------------------
__global__ __launch_bounds__(256) void corr_gemm(const float* __restrict__ fq,
                                                 const float* __restrict__ fs,
                                                 const float* __restrict__ invn,
                                                 float* __restrict__ corr) {
    __shared__ float As[16][64];
    __shared__ float Bs[16][64];
    int lb = blockIdx.z;
    int l = lb >> 1, b = lb & 1;          // lb = l*B + b (feature layout)
    int i0 = blockIdx.y * 64, j0 = blockIdx.x * 64;
    int tid = threadIdx.x;
    int tx = tid & 15, ty = tid >> 4;
    int lcol = tid & 63, lrow = tid >> 6; // loader mapping
    const float* A = fq + (size_t)lb * CF * HW;
    const float* Bm = fs + (size_t)lb * CF * HW;
    bool aok = (i0 + lcol) < HW;
    bool bok = (j0 + lcol) < HW;
    float acc[4][4];
    #pragma unroll
    for (int r = 0; r < 4; ++r)
        #pragma unroll
        for (int c = 0; c < 4; ++c) acc[r][c] = 0.f;

    for (int c0 = 0; c0 < CF; c0 += 16) {
        __syncthreads();
        #pragma unroll
        for (int r = 0; r < 4; ++r) {
            int row = c0 + lrow + r * 4;
            As[lrow + r * 4][lcol] = aok ? A[(size_t)row * HW + i0 + lcol] : 0.f;
            Bs[lrow + r * 4][lcol] = bok ? Bm[(size_t)row * HW + j0 + lcol] : 0.f;
        }
        __syncthreads();
        #pragma unroll
        for (int kk = 0; kk < 16; ++kk) {
            float4 a4 = *(const float4*)&As[kk][ty * 4];
            float4 b4 = *(const float4*)&Bs[kk][tx * 4];
            float av[4] = {a4.x, a4.y, a4.z, a4.w};
            float bv[4] = {b4.x, b4.y, b4.z, b4.w};
            #pragma unroll
            for (int r = 0; r < 4; ++r)
                #pragma unroll
                for (int c = 0; c < 4; ++c)
                    acc[r][c] = fmaf(av[r], bv[c], acc[r][c]);
        }
    }
    int obase = (b * 9 + l) * HW;
    #pragma unroll
    for (int r = 0; r < 4; ++r) {
        int ij = i0 + ty * 4 + r;
        if (ij >= HW) continue;
        float iq = invn[lb * HW + ij];
        #pragma unroll
        for (int c = 0; c < 4; ++c) {
            int km = j0 + tx * 4 + c;
            if (km >= HW) continue;
            float is = invn[7200 + lb * HW + km];
            corr[(size_t)(obase + ij) * HW + km] = acc[r][c] * iq * is;
        }
    }
}

// ---------------------------------------------------------------------------
// Kernel 4: 4D conv (3x3x3x3, pad 1) + ReLU.
// in: [B][CIN][400(ij)][400(km)], wt: [COUT][CIN][3][3][3][3]
// SWAP: use wt[co][ci][dk][dm][di][dj] (transposed-path trick).
// ACCUM: out += relu(conv) instead of store.
// grid (400, B), block 512 (threads 400..511 idle in compute).
// ---------------------------------------------------------------------------
template <int CIN, int COUT, bool SWAP, bool ACCUM>
__global__ __launch_bounds__(512) void conv4d_relu(const float* __restrict__ in,
                                                   const float* __restrict__ wt,
                                                   float* __restrict__ out) {
    __shared__ float planes[9][484];   // 22x22 zero-halo planes
    int b = blockIdx.y;
    int ij = blockIdx.x;
    int i = ij / 20, j = ij - (ij / 20) * 20;
    int tid = threadIdx.x;
    float acc[COUT];
    #pragma unroll
    for (int co = 0; co < COUT; ++co) acc[co] = 0.f;

    for (int p = tid; p < 9 * 484; p += 512) (&planes[0][0])[p] = 0.f;

    int pos = tid;
    int k = pos / 20, m = pos - (pos / 20) * 20;  // valid when pos < 400

    #pragma unroll 1
    for (int cin = 0; cin < CIN; ++cin) {
        __syncthreads();
        for (int idx = tid; idx < 9 * HW; idx += 512) {
            int pl = idx / HW;
            int rem = idx - pl * HW;
            int di = pl / 3, dj = pl - (pl / 3) * 3;
            int ii = i + di - 1, jj = j + dj - 1;
            float v = 0.f;
            if (ii >= 0 && ii < 20 && jj >= 0 && jj < 20)
                v = in[((size_t)(b * CIN + cin) * HW + ii * 20 + jj) * HW + rem];
            int kk = rem / 20, mm = rem - (rem / 20) * 20;
            planes[pl][(kk + 1) * 22 + mm + 1] = v;
        }
        __syncthreads();
        if (pos < HW) {
            #pragma unroll
            for (int pl = 0; pl < 9; ++pl) {
                float vv[9];
                int base = k * 22 + m;
                #pragma unroll
                for (int dk = 0; dk < 3; ++dk)
                    #pragma unroll
                    for (int dm = 0; dm < 3; ++dm)
                        vv[dk * 3 + dm] = planes[pl][base + dk * 22 + dm];
                const int di = pl / 3, dj = pl % 3;
                #pragma unroll
                for (int co = 0; co < COUT; ++co) {
                    #pragma unroll
                    for (int dd = 0; dd < 9; ++dd) {
                        const int dk = dd / 3, dm = dd % 3;
                        int widx = SWAP
                            ? ((((co * CIN + cin) * 3 + dk) * 3 + dm) * 3 + di) * 3 + dj
                            : ((((co * CIN + cin) * 3 + di) * 3 + dj) * 3 + dk) * 3 + dm;
                        acc[co] = fmaf(vv[dd], wt[widx], acc[co]);
                    }
                }
            }
        }
    }
    if (pos < HW) {
        #pragma unroll
        for (int co = 0; co < COUT; ++co) {
            float r = fmaxf(acc[co], 0.f);
            size_t o = ((size_t)(b * COUT + co) * HW + ij) * HW + pos;
            if (ACCUM) out[o] += r; else out[o] = r;
        }
    }
}

// ---------------------------------------------------------------------------
// Kernel 5: softmax over s (row of 400, scaled by TEMP) + att_fq = attn . V
// grid (400, B), block 256. att_out[b][c][q]
// ---------------------------------------------------------------------------
__global__ __launch_bounds__(256) void softmax_av(const float* __restrict__ c4,
                                                  const float* __restrict__ f_s,
                                                  float* __restrict__ att_out) {
    __shared__ float p[HW];
    __shared__ float red[256];
    int b = blockIdx.y, q = blockIdx.x;
    int tid = threadIdx.x;
    const float* row = c4 + ((size_t)b * HW + q) * HW;
    float v0 = row[tid] * TEMPF;
    float v1 = (tid < HW - 256) ? row[tid + 256] * TEMPF : -1e30f;
    red[tid] = fmaxf(v0, v1);
    __syncthreads();
    for (int s = 128; s > 0; s >>= 1) {
        if (tid < s) red[tid] = fmaxf(red[tid], red[tid + s]);
        __syncthreads();
    }
    float mx = red[0];
    __syncthreads();
    float e0 = expf(v0 - mx);
    float e1 = (tid < HW - 256) ? expf(v1 - mx) : 0.f;
    p[tid] = e0;
    if (tid < HW - 256) p[tid + 256] = e1;
    red[tid] = e0 + e1;
    __syncthreads();
    for (int s = 128; s > 0; s >>= 1) {
        if (tid < s) red[tid] += red[tid + s];
        __syncthreads();
    }
    float inv = 1.0f / red[0];
    // phase 2: thread = channel c
    const float* vrow = f_s + (size_t)(b * CH + tid) * HW;
    float acc = 0.f;
    for (int s = 0; s < HW; ++s) acc = fmaf(p[s], vrow[s], acc);
    att_out[(size_t)(b * CH + tid) * HW + q] = acc * inv;
}

// ---------------------------------------------------------------------------
// Kernel 6: fq = l2norm(f_q, ch) + 0.5 * l2norm(att_fq, ch)
// grid (400, B), block 256 (thread = channel)
// ---------------------------------------------------------------------------
__global__ __launch_bounds__(256) void final_fq(const float* __restrict__ f_q,
                                                const float* __restrict__ att,
                                                float* __restrict__ out_fq) {
    __shared__ float red[256];
    int b = blockIdx.y, q = blockIdx.x;
    int tid = threadIdx.x;
    size_t idx = (size_t)(b * CH + tid) * HW + q;
    float f = f_q[idx];
    float a = att[idx];
    red[tid] = f * f;
    __syncthreads();
    for (int s = 128; s > 0; s >>= 1) {
        if (tid < s) red[tid] += red[tid + s];
        __syncthreads();
    }
    float invf = 1.0f / fmaxf(sqrtf(red[0]), EPSF);
    __syncthreads();
    red[tid] = a * a;
    __syncthreads();
    for (int s = 128; s > 0; s >>= 1) {
        if (tid < s) red[tid] += red[tid + s];
        __syncthreads();
    }
    float inva = 1.0f / fmaxf(sqrtf(red[0]), EPSF);
    out_fq[idx] = f * invf + 0.5f * a * inva;
}

// ---------------------------------------------------------------------------
extern "C" void kernel_launch(void* const* d_in, const int* in_sizes, int n_in,
                              void* d_out, int out_size, void* d_ws, size_t ws_size,
                              hipStream_t stream) {
    const float* fq_feats = (const float*)d_in[0];
    const float* fs_feats = (const float*)d_in[1];
    const float* f_q      = (const float*)d_in[2];
    const float* f_s      = (const float*)d_in[3];
    const float* w1       = (const float*)d_in[4];
    const float* w2       = (const float*)d_in[5];
    const float* w3       = (const float*)d_in[6];
    float* out = (float*)d_out;              // fq at 0, att_fq at 204800

    float* ws      = (float*)d_ws;
    float* partial = ws;                     // 115200
    float* invn    = partial + 115200;       // 14400
    float* corr    = invn + 14400;           // 2,880,000
    float* buf1    = corr + 2880000;         // 3,200,000
    float* buf2    = buf1 + 3200000;         // 3,200,000
    float* c4      = buf2 + 3200000;         // 320,000
    float* att     = out + 204800;

    norm_partial<<<dim3(18 * 8, 2), 256, 0, stream>>>(fq_feats, fs_feats, partial);
    norm_finalize<<<(2 * 18 * HW + 255) / 256, 256, 0, stream>>>(partial, invn);
    corr_gemm<<<dim3(7, 7, 18), 256, 0, stream>>>(fq_feats, fs_feats, invn, corr);

    // path A (identity orientation)
    conv4d_relu<9, 10, false, false><<<dim3(400, NB), 512, 0, stream>>>(corr, w1, buf1);
    conv4d_relu<10, 10, false, false><<<dim3(400, NB), 512, 0, stream>>>(buf1, w2, buf2);
    conv4d_relu<10, 1, false, false><<<dim3(400, NB), 512, 0, stream>>>(buf2, w3, c4);
    // path B (transposed path folded via tap-swapped weights), accumulated
    conv4d_relu<9, 10, true, false><<<dim3(400, NB), 512, 0, stream>>>(corr, w1, buf1);
    conv4d_relu<10, 10, true, false><<<dim3(400, NB), 512, 0, stream>>>(buf1, w2, buf2);
    conv4d_relu<10, 1, true, true><<<dim3(400, NB), 512, 0, stream>>>(buf2, w3, c4);

    softmax_av<<<dim3(400, NB), 256, 0, stream>>>(c4, f_s, att);
    final_fq<<<dim3(400, NB), 256, 0, stream>>>(f_q, att, out);

    (void)in_sizes; (void)n_in; (void)out_size; (void)ws_size;
}

// Round 2
// 926.598 us; speedup vs baseline: 4.9053x; 4.9053x over previous
//
#include <hip/hip_runtime.h>
#include <math.h>
#include <stddef.h>

#define L9   9
#define NB   2
#define CF   1024
#define HW   400     // 20*20
#define CH   256
#define TEMPF 20.0f
#define EPSF  1e-12f

// ---------------------------------------------------------------------------
// Kernel 1: partial sums of squares over C for l2norm of fq_feats / fs_feats.
// ---------------------------------------------------------------------------
__global__ __launch_bounds__(256) void norm_partial(const float* __restrict__ fq,
                                                    const float* __restrict__ fs,
                                                    float* __restrict__ partial) {
    int t = blockIdx.y;
    int lb = blockIdx.x >> 3;
    int chunk = blockIdx.x & 7;
    const float* src = (t == 0 ? fq : fs) + (size_t)lb * CF * HW;
    int c0 = chunk * 128;
    int tid = threadIdx.x;
    float acc0 = 0.f, acc1 = 0.f;
    for (int c = c0; c < c0 + 128; ++c) {
        const float* row = src + (size_t)c * HW;
        float v0 = row[tid];
        acc0 = fmaf(v0, v0, acc0);
        if (tid < HW - 256) { float v1 = row[tid + 256]; acc1 = fmaf(v1, v1, acc1); }
    }
    float* dst = partial + ((size_t)(t * 18 + lb) * 8 + chunk) * HW;
    dst[tid] = acc0;
    if (tid < HW - 256) dst[tid + 256] = acc1;
}

// ---------------------------------------------------------------------------
// Kernel 2: finalize inverse norms.
// ---------------------------------------------------------------------------
__global__ __launch_bounds__(256) void norm_finalize(const float* __restrict__ partial,
                                                     float* __restrict__ invn) {
    int idx = blockIdx.x * 256 + threadIdx.x;
    if (idx >= 2 * 18 * HW) return;
    int t_lb = idx / HW;
    int ij = idx - t_lb * HW;
    const float* p = partial + (size_t)t_lb * 8 * HW + ij;
    float ss = 0.f;
    #pragma unroll
    for (int c = 0; c < 8; ++c) ss += p[c * HW];
    invn[idx] = 1.0f / fmaxf(sqrtf(ss), EPSF);
}

// ---------------------------------------------------------------------------
// Kernel 3: correlation GEMM per (l,b) — unchanged from R0 (correct).
// ---------------------------------------------------------------------------
__global__ __launch_bounds__(256) void corr_gemm(const float* __restrict__ fq,
                                                 const float* __restrict__ fs,
                                                 const float* __restrict__ invn,
                                                 float* __restrict__ corr) {
    __shared__ float As[16][64];
    __shared__ float Bs[16][64];
    int lb = blockIdx.z;
    int l = lb >> 1, b = lb & 1;
    int i0 = blockIdx.y * 64, j0 = blockIdx.x * 64;
    int tid = threadIdx.x;
    int tx = tid & 15, ty = tid >> 4;
    int lcol = tid & 63, lrow = tid >> 6;
    const float* A = fq + (size_t)lb * CF * HW;
    const float* Bm = fs + (size_t)lb * CF * HW;
    bool aok = (i0 + lcol) < HW;
    bool bok = (j0 + lcol) < HW;
    float acc[4][4];
    #pragma unroll
    for (int r = 0; r < 4; ++r)
        #pragma unroll
        for (int c = 0; c < 4; ++c) acc[r][c] = 0.f;

    for (int c0 = 0; c0 < CF; c0 += 16) {
        __syncthreads();
        #pragma unroll
        for (int r = 0; r < 4; ++r) {
            int row = c0 + lrow + r * 4;
            As[lrow + r * 4][lcol] = aok ? A[(size_t)row * HW + i0 + lcol] : 0.f;
            Bs[lrow + r * 4][lcol] = bok ? Bm[(size_t)row * HW + j0 + lcol] : 0.f;
        }
        __syncthreads();
        #pragma unroll
        for (int kk = 0; kk < 16; ++kk) {
            float4 a4 = *(const float4*)&As[kk][ty * 4];
            float4 b4 = *(const float4*)&Bs[kk][tx * 4];
            float av[4] = {a4.x, a4.y, a4.z, a4.w};
            float bv[4] = {b4.x, b4.y, b4.z, b4.w};
            #pragma unroll
            for (int r = 0; r < 4; ++r)
                #pragma unroll
                for (int c = 0; c < 4; ++c)
                    acc[r][c] = fmaf(av[r], bv[c], acc[r][c]);
        }
    }
    int obase = (b * 9 + l) * HW;
    #pragma unroll
    for (int r = 0; r < 4; ++r) {
        int ij = i0 + ty * 4 + r;
        if (ij >= HW) continue;
        float iq = invn[lb * HW + ij];
        #pragma unroll
        for (int c = 0; c < 4; ++c) {
            int km = j0 + tx * 4 + c;
            if (km >= HW) continue;
            float is = invn[7200 + lb * HW + km];
            corr[(size_t)(obase + ij) * HW + km] = acc[r][c] * iq * is;
        }
    }
}

// ---------------------------------------------------------------------------
// Kernel 4 (v2): 4D conv (3x3x3x3, pad 1) + ReLU.
// Block = (b, ij). 256 threads: lanes t<200 compute, t=k*10+g owns output
// m-pair (2g, 2g+1) of row k.  LDS: 9 halo planes [22 rows][28 cols],
// interior at col 4, col 3 = m=-1 halo, col 24 = m=20 halo (zeros).
// Inner loop per (cin,pl): 9 LDS window insts + 180 FMAs (COUT=10).
// Weights via uniform (scalar) loads — scalar pipe co-issues with VALU.
// ---------------------------------------------------------------------------
template <int CIN, int COUT, bool SWAP, bool ACCUM>
__global__ __launch_bounds__(256) void conv4d_v2(const float* __restrict__ in,
                                                 const float* __restrict__ wt,
                                                 float* __restrict__ out) {
    __shared__ float planes[9][22][28];   // 22,176 B
    const int b  = blockIdx.y;
    const int ij = blockIdx.x;
    const int i = ij / 20, j = ij - (ij / 20) * 20;
    const int tid = threadIdx.x;

    // zero everything once (halo stays zero; interior rewritten per cin)
    float* flat = &planes[0][0][0];
    for (int p = tid; p < 9 * 22 * 28; p += 256) flat[p] = 0.f;

    // worker mapping
    const bool worker = tid < 200;
    const int k = tid / 10;             // 0..19 (garbage for t>=200, unused)
    const int g = tid - k * 10;         // 0..9  -> m0 = 2g

    float acc[COUT][2];
    #pragma unroll
    for (int co = 0; co < COUT; ++co) { acc[co][0] = 0.f; acc[co][1] = 0.f; }

    const float* in_b = in + (size_t)b * CIN * HW * HW;

    #pragma unroll 1
    for (int cin = 0; cin < CIN; ++cin) {
        __syncthreads();   // previous compute done reading LDS
        const float* in_cin = in_b + (size_t)cin * HW * HW;
        // stage 9 plane interiors: 900 float4 slots
        for (int idx = tid; idx < 900; idx += 256) {
            int pl = idx / 100;
            int e  = idx - pl * 100;          // float4 slot within plane
            int di = pl / 3, dj = pl - (pl / 3) * 3;
            int ii = i + di - 1, jj = j + dj - 1;
            if ((unsigned)ii < 20u && (unsigned)jj < 20u) {
                const float4 v = *(const float4*)(in_cin + (size_t)(ii * 20 + jj) * HW + e * 4);
                int kk = e / 5, c4 = e - kk * 5;
                *(float4*)&planes[pl][kk + 1][4 + 4 * c4] = v;
            }
        }
        __syncthreads();

        if (worker) {
            #pragma unroll 1
            for (int pl = 0; pl < 9; ++pl) {
                float vv[3][4];
                #pragma unroll
                for (int dk = 0; dk < 3; ++dk) {
                    const float* rowp = &planes[pl][k + dk][3 + 2 * g];
                    vv[dk][0] = rowp[0]; vv[dk][1] = rowp[1];
                    vv[dk][2] = rowp[2]; vv[dk][3] = rowp[3];
                }
                #pragma unroll
                for (int co = 0; co < COUT; ++co) {
                    const int base = (co * CIN + cin) * 81;
                    #pragma unroll
                    for (int dd = 0; dd < 9; ++dd) {
                        const int dk = dd / 3, dm = dd % 3;
                        const float w = SWAP ? wt[base + dd * 9 + pl]
                                             : wt[base + pl * 9 + dd];
                        acc[co][0] = fmaf(w, vv[dk][dm],     acc[co][0]);
                        acc[co][1] = fmaf(w, vv[dk][dm + 1], acc[co][1]);
                    }
                }
            }
        }
    }

    if (worker) {
        const int km = k * 20 + 2 * g;
        #pragma unroll
        for (int co = 0; co < COUT; ++co) {
            float r0 = fmaxf(acc[co][0], 0.f);
            float r1 = fmaxf(acc[co][1], 0.f);
            size_t o = ((size_t)(b * COUT + co) * HW + ij) * HW + km;
            if (ACCUM) { out[o] += r0; out[o + 1] += r1; }
            else { float2 v = make_float2(r0, r1); *(float2*)(out + o) = v; }
        }
    }
}

// ---------------------------------------------------------------------------
// Kernel 5: softmax over s + att_fq = attn . V
// ---------------------------------------------------------------------------
__global__ __launch_bounds__(256) void softmax_av(const float* __restrict__ c4,
                                                  const float* __restrict__ f_s,
                                                  float* __restrict__ att_out) {
    __shared__ float p[HW];
    __shared__ float red[256];
    int b = blockIdx.y, q = blockIdx.x;
    int tid = threadIdx.x;
    const float* row = c4 + ((size_t)b * HW + q) * HW;
    float v0 = row[tid] * TEMPF;
    float v1 = (tid < HW - 256) ? row[tid + 256] * TEMPF : -1e30f;
    red[tid] = fmaxf(v0, v1);
    __syncthreads();
    for (int s = 128; s > 0; s >>= 1) {
        if (tid < s) red[tid] = fmaxf(red[tid], red[tid + s]);
        __syncthreads();
    }
    float mx = red[0];
    __syncthreads();
    float e0 = expf(v0 - mx);
    float e1 = (tid < HW - 256) ? expf(v1 - mx) : 0.f;
    p[tid] = e0;
    if (tid < HW - 256) p[tid + 256] = e1;
    red[tid] = e0 + e1;
    __syncthreads();
    for (int s = 128; s > 0; s >>= 1) {
        if (tid < s) red[tid] += red[tid + s];
        __syncthreads();
    }
    float inv = 1.0f / red[0];
    const float* vrow = f_s + (size_t)(b * CH + tid) * HW;
    float acc = 0.f;
    for (int s = 0; s < HW; ++s) acc = fmaf(p[s], vrow[s], acc);
    att_out[(size_t)(b * CH + tid) * HW + q] = acc * inv;
}

// ---------------------------------------------------------------------------
// Kernel 6: fq = l2norm(f_q, ch) + 0.5 * l2norm(att_fq, ch)
// ---------------------------------------------------------------------------
__global__ __launch_bounds__(256) void final_fq(const float* __restrict__ f_q,
                                                const float* __restrict__ att,
                                                float* __restrict__ out_fq) {
    __shared__ float red[256];
    int b = blockIdx.y, q = blockIdx.x;
    int tid = threadIdx.x;
    size_t idx = (size_t)(b * CH + tid) * HW + q;
    float f = f_q[idx];
    float a = att[idx];
    red[tid] = f * f;
    __syncthreads();
    for (int s = 128; s > 0; s >>= 1) {
        if (tid < s) red[tid] += red[tid + s];
        __syncthreads();
    }
    float invf = 1.0f / fmaxf(sqrtf(red[0]), EPSF);
    __syncthreads();
    red[tid] = a * a;
    __syncthreads();
    for (int s = 128; s > 0; s >>= 1) {
        if (tid < s) red[tid] += red[tid + s];
        __syncthreads();
    }
    float inva = 1.0f / fmaxf(sqrtf(red[0]), EPSF);
    out_fq[idx] = f * invf + 0.5f * a * inva;
}

// ---------------------------------------------------------------------------
extern "C" void kernel_launch(void* const* d_in, const int* in_sizes, int n_in,
                              void* d_out, int out_size, void* d_ws, size_t ws_size,
                              hipStream_t stream) {
    const float* fq_feats = (const float*)d_in[0];
    const float* fs_feats = (const float*)d_in[1];
    const float* f_q      = (const float*)d_in[2];
    const float* f_s      = (const float*)d_in[3];
    const float* w1       = (const float*)d_in[4];
    const float* w2       = (const float*)d_in[5];
    const float* w3       = (const float*)d_in[6];
    float* out = (float*)d_out;              // fq at 0, att_fq at 204800

    float* ws      = (float*)d_ws;
    float* partial = ws;                     // 115,200
    float* invn    = partial + 115200;       // 14,400
    float* corr    = invn + 14400;           // 2,880,000
    float* buf1    = corr + 2880000;         // 3,200,000
    float* buf2    = buf1 + 3200000;         // 3,200,000
    float* c4      = buf2 + 3200000;         // 320,000
    float* att     = out + 204800;

    norm_partial<<<dim3(18 * 8, 2), 256, 0, stream>>>(fq_feats, fs_feats, partial);
    norm_finalize<<<(2 * 18 * HW + 255) / 256, 256, 0, stream>>>(partial, invn);
    corr_gemm<<<dim3(7, 7, 18), 256, 0, stream>>>(fq_feats, fs_feats, invn, corr);

    // path A (identity orientation)
    conv4d_v2<9, 10, false, false><<<dim3(400, NB), 256, 0, stream>>>(corr, w1, buf1);
    conv4d_v2<10, 10, false, false><<<dim3(400, NB), 256, 0, stream>>>(buf1, w2, buf2);
    conv4d_v2<10, 1, false, false><<<dim3(400, NB), 256, 0, stream>>>(buf2, w3, c4);
    // path B (transposed path folded via tap-swapped weights)
    conv4d_v2<9, 10, true, false><<<dim3(400, NB), 256, 0, stream>>>(corr, w1, buf1);
    conv4d_v2<10, 10, true, false><<<dim3(400, NB), 256, 0, stream>>>(buf1, w2, buf2);
    conv4d_v2<10, 1, true, true><<<dim3(400, NB), 256, 0, stream>>>(buf2, w3, c4);

    softmax_av<<<dim3(400, NB), 256, 0, stream>>>(c4, f_s, att);
    final_fq<<<dim3(400, NB), 256, 0, stream>>>(f_q, att, out);

    (void)in_sizes; (void)n_in; (void)out_size; (void)ws_size;
}